// Round 14
// baseline (931.711 us; speedup 1.0000x reference)
//
#include <hip/hip_runtime.h>

// LSTM_77893526880768: B=T=F=H=256.  256 independent row-chains, 255 steps.
//
// v23 = v22 recurrent VERBATIM (591us, reproduced twice) + precompute
//       4-way row-split for occupancy.
//
// Evidence ladder (recurrent step, cy @ ~700-750MHz fixed clock):
//   rows/WG sweep: 16->3670 | 8->3100 | *2->1630* | 1->1755.  Minimum at 2.
//   More M-packing needs cross-WG h exchange (measured ~4.7us/round, dead).
//   Weights: 192 regs (i,f,g) + o-gate LDS is the unique no-spill split
//   (v18/v19 falsified 256/128-reg variants).  Conflicts/shuffles are
//   overlapped, not critical (v20/v21).  => recurrent is at its structural
//   floor; untouched this round.
//
// v23's single change: lstm_precompute grid (255,1) -> (255,4).
//   v22's config was 255 WGs = 1/CU, 1 wave/SIMD: latency-starved (serial
//   nbi loop, no co-resident waves), ~110us for ~50us of traffic.
//   Now block y owns row-quarter y*64..y*64+63 (one 16-row tile per wave,
//   rt gone): x still read ONCE chip-wide (row-partitioned); WxT re-reads
//   are L2-resident (512KB/XCD).  1020 WGs ~= 4 blocks/CU
//   (__launch_bounds__(256,4)) -> 4 waves/SIMD hide L2/HBM latency.
//   Same MFMA total, same P layout/bytes.
//
// Workspace layout:
//   [0, 512K)       WxT bf16   (dead after precompute)
//   [512K, 1M)      WhT bf16
//   [1M, 1M+4K)     bcat fp32
//   [1M+4K, ...)    P bf16  [t][rg16][n][16] = 133,693,440 B

#define STEPS 255

typedef short bf16x8 __attribute__((ext_vector_type(8)));
typedef short bf16x4 __attribute__((ext_vector_type(4)));
typedef float f32x4  __attribute__((ext_vector_type(4)));

__device__ inline unsigned short f2bf(float f) {
  unsigned int u = __float_as_uint(f);
  unsigned int r = (u + 0x7FFFu + ((u >> 16) & 1u)) >> 16;  // RNE
  return (unsigned short)r;
}
__device__ inline float bf2f(unsigned short s) {
  return __uint_as_float(((unsigned int)s) << 16);
}
__device__ inline float sig_f(float x) {
  float e = exp2f(-1.442695041f * x);
  return __builtin_amdgcn_rcpf(1.0f + e);
}
__device__ inline float tanh_f(float x) {
  float e = exp2f(-2.885390082f * x);
  return 2.0f * __builtin_amdgcn_rcpf(1.0f + e) - 1.0f;
}

// ---------- prep: W transpose (W[k][j] fp32 -> WT[g*256+j][k] bf16) ----------
__global__ __launch_bounds__(256) void lstm_prep_w(
    const float* __restrict__ m0, const float* __restrict__ m1,
    const float* __restrict__ m2, const float* __restrict__ m3,
    const float* __restrict__ m4, const float* __restrict__ m5,
    const float* __restrict__ m6, const float* __restrict__ m7,
    unsigned short* __restrict__ WxT, unsigned short* __restrict__ WhT) {
  const float* mats[8] = {m0, m1, m2, m3, m4, m5, m6, m7};
  int mat = blockIdx.z;
  const float* W = mats[mat];
  unsigned short* out = (mat < 4 ? WxT : WhT) + (size_t)(mat & 3) * 256 * 256;
  int kblk = blockIdx.x * 32, jblk = blockIdx.y * 32;
  __shared__ float tile[32][33];
  int tx = threadIdx.x & 31, ty = threadIdx.x >> 5;
#pragma unroll
  for (int i = 0; i < 4; ++i) {
    int kk = ty + i * 8;
    tile[kk][tx] = W[(size_t)(kblk + kk) * 256 + jblk + tx];
  }
  __syncthreads();
#pragma unroll
  for (int i = 0; i < 4; ++i) {
    int jj = ty + i * 8;
    out[(size_t)(jblk + jj) * 256 + kblk + tx] = f2bf(tile[tx][jj]);
  }
}

// ---------- prep: bias fold ----------
__global__ void lstm_prep_b(
    const float* __restrict__ bx0, const float* __restrict__ bx1,
    const float* __restrict__ bx2, const float* __restrict__ bx3,
    const float* __restrict__ bh0, const float* __restrict__ bh1,
    const float* __restrict__ bh2, const float* __restrict__ bh3,
    float* __restrict__ bcat) {
  const float* bx[4] = {bx0, bx1, bx2, bx3};
  const float* bh[4] = {bh0, bh1, bh2, bh3};
  int i = blockIdx.x * 256 + threadIdx.x;
  int g = i >> 8, j = i & 255;
  bcat[i] = bx[g][j] + bh[g][j];
}

// ---------- precompute: P[t][rg16][n][rl] = bcat[n] + sum_k x[r,t,k] Wx[k,n] ----------
// v23: grid (255,4).  Block y owns rows [y*64, y*64+64); wave w covers the
// 16-row tile rbase = y*64 + w*16 (rg16 = y*4 + w).  x read once chip-wide.
__global__ __launch_bounds__(256, 4) void lstm_precompute(
    const float* __restrict__ x, const unsigned short* __restrict__ WxT,
    const float* __restrict__ bcat, unsigned short* __restrict__ P) {
  int t = blockIdx.x;
  int y = blockIdx.y;
  int tid = threadIdx.x;
  int w = tid >> 6, lane = tid & 63, q = lane >> 4, cl = lane & 15;
  int rbase = y * 64 + w * 16;
  int rg16 = y * 4 + w;

  bf16x8 bfrag[8];
#pragma unroll
  for (int kt = 0; kt < 8; ++kt) {
    int k0 = kt * 32 + q * 8;
    const float* xp = x + (((size_t)(rbase + cl) * 256 + t) * 256 + k0);
    f32x4 lo = *(const f32x4*)xp;
    f32x4 hi = *(const f32x4*)(xp + 4);
    bf16x8 bv;
    bv[0] = (short)f2bf(lo[0]); bv[1] = (short)f2bf(lo[1]);
    bv[2] = (short)f2bf(lo[2]); bv[3] = (short)f2bf(lo[3]);
    bv[4] = (short)f2bf(hi[0]); bv[5] = (short)f2bf(hi[1]);
    bv[6] = (short)f2bf(hi[2]); bv[7] = (short)f2bf(hi[3]);
    bfrag[kt] = bv;
  }

  for (int nbi = 0; nbi < 16; ++nbi) {
    int nblk = nbi * 64;
    f32x4 acc[4];
#pragma unroll
    for (int a = 0; a < 4; ++a) acc[a] = f32x4{0.f, 0.f, 0.f, 0.f};

#pragma unroll
    for (int kt = 0; kt < 8; ++kt) {
      int k0 = kt * 32 + q * 8;
      bf16x8 afrag[4];
#pragma unroll
      for (int mt = 0; mt < 4; ++mt)
        afrag[mt] = *(const bf16x8*)(WxT + (size_t)(nblk + mt * 16 + cl) * 256 + k0);
#pragma unroll
      for (int mt = 0; mt < 4; ++mt)
        acc[mt] = __builtin_amdgcn_mfma_f32_16x16x32_bf16(
            afrag[mt], bfrag[kt], acc[mt], 0, 0, 0);
    }
#pragma unroll
    for (int mt = 0; mt < 4; ++mt) {
#pragma unroll
      for (int reg = 0; reg < 4; ++reg) {
        int n = nblk + mt * 16 + q * 4 + reg;
        P[(((size_t)t * 16 + rg16) * 1024 + n) * 16 + cl] = f2bf(acc[mt][reg] + bcat[n]);
      }
    }
  }
}

// ---------- recurrent (v17/v22, verified 591us): 128 WGs x 2 rows ----------
__global__ __launch_bounds__(512, 2) void lstm_recurrent(
    const unsigned short* __restrict__ WhT,
    const unsigned short* __restrict__ P,
    float* __restrict__ out) {
  // o-gate B-frags: [wave][block][kt][lane] bf16x8 = 128 KB (v5-proven layout)
  __shared__ bf16x8 o_w[8][2][8][64];
  // h double buffer, XOR-swizzled: byte ^= ((row&7)<<4).  16 KB.
  // Rows 0..1 live; rows 2..15 stay zero forever (A-tile zero-padding).
  __shared__ unsigned short hbuf[2][16 * 256];

  int tid = threadIdx.x;
  int w = tid >> 6, lane = tid & 63, q = lane >> 4, cl = lane & 15;
  // XCD swizzle (v17-proven): the 8 WGs sharing P lines (same x>>3) get
  // identical b%8 -> one XCD -> each P line fetched into exactly one L2.
  int b_ = blockIdx.x;
  int x = (b_ & 7) * 16 + (b_ >> 3);  // bijective 0..127
  int rg16 = x >> 3;            // P row-group (global row >> 4)
  int idxb = (x & 7) * 2;       // P idx15 base for this WG's rows

  // ---- stage o-gate tiles into LDS: 8192 16B-chunks, 16 per thread
  for (int i = 0; i < 16; ++i) {
    int idx = tid + i * 512;
    int sw = idx >> 10, sb = (idx >> 9) & 1, skt = (idx >> 6) & 7, sl = idx & 63;
    int sq = sl >> 4, scl = sl & 15;
    int col = (2 * sw + sb) * 16 + scl;
    int k0 = skt * 32 + sq * 8;
    o_w[sw][sb][skt][sl] = *(const bf16x8*)(WhT + (size_t)(3 * 256 + col) * 256 + k0);
  }

  // ---- i,f,g gate tiles into VGPRs (static indexing only -- rule #20)
  bf16x8 wreg[2][3][8];  // [block][gate][kt] = 48 frags
#pragma unroll
  for (int b = 0; b < 2; ++b)
#pragma unroll
    for (int g = 0; g < 3; ++g)
#pragma unroll
      for (int kt = 0; kt < 8; ++kt) {
        int col = (2 * w + b) * 16 + cl;
        wreg[b][g][kt] =
            *(const bf16x8*)(WhT + (size_t)(g * 256 + col) * 256 + kt * 32 + q * 8);
      }

  // ---- zero BOTH h buffers (rows 2..15 never written; h_0 = 0)
  for (int i = tid; i < 4096; i += 512) ((unsigned int*)&hbuf[0][0])[i] = 0;

  // Memory clobber (v15-proven): rematerializing the wreg global loads
  // across this fence is illegal => weight values stay register-resident.
  asm volatile("" ::: "memory");
  __syncthreads();

  // A-read base (t-independent): row = cl, k-offset q*16 within kt-block,
  // swizzled.  Per kt: byte = abase ^ (kt*64) (bit-disjoint, v12-proven).
  int abase = cl * 512 + ((q * 16) ^ ((cl & 7) << 4));

  // EW ownership: lane (q,cl) owns the single cell
  //   block bq = q>>1, local row rq = q&1, col = 32w + bq*16 + cl.
  int bq = q >> 1, rq = q & 1;
  int colq = 32 * w + bq * 16 + cl;
  int idx15 = idxb + rq;

  float creg = 0.f;

  for (int t = 0; t < STEPS; ++t) {
    int rb = t & 1;
    bool lastt = (t == STEPS - 1);
    const unsigned short* hr = &hbuf[rb][0];
    unsigned short* hw = &hbuf[rb ^ 1][0];

    // P loads for this lane's cell: issued at step start, consumed after
    // the MFMA phase -> L2/HBM latency stays hidden.
    unsigned short pv[4];
    {
      const unsigned short* pp =
          P + (((size_t)t * 16 + rg16) * 1024 + colq) * 16 + idx15;
#pragma unroll
      for (int g = 0; g < 4; ++g) pv[g] = pp[(size_t)g * 4096];
    }

    // ---- MFMA: af loaded once per kt, feeds both blocks x 4 gates
    f32x4 acc[2][4];
#pragma unroll
    for (int b = 0; b < 2; ++b)
#pragma unroll
      for (int g = 0; g < 4; ++g) acc[b][g] = f32x4{0.f, 0.f, 0.f, 0.f};

#pragma unroll
    for (int kt = 0; kt < 8; ++kt) {
      bf16x8 af = *(const bf16x8*)(hr + ((abase ^ (kt * 64)) >> 1));
      acc[0][0] = __builtin_amdgcn_mfma_f32_16x16x32_bf16(af, wreg[0][0][kt], acc[0][0], 0, 0, 0);
      acc[0][1] = __builtin_amdgcn_mfma_f32_16x16x32_bf16(af, wreg[0][1][kt], acc[0][1], 0, 0, 0);
      acc[0][2] = __builtin_amdgcn_mfma_f32_16x16x32_bf16(af, wreg[0][2][kt], acc[0][2], 0, 0, 0);
      acc[0][3] = __builtin_amdgcn_mfma_f32_16x16x32_bf16(af, o_w[w][0][kt][lane], acc[0][3], 0, 0, 0);
      acc[1][0] = __builtin_amdgcn_mfma_f32_16x16x32_bf16(af, wreg[1][0][kt], acc[1][0], 0, 0, 0);
      acc[1][1] = __builtin_amdgcn_mfma_f32_16x16x32_bf16(af, wreg[1][1][kt], acc[1][1], 0, 0, 0);
      acc[1][2] = __builtin_amdgcn_mfma_f32_16x16x32_bf16(af, wreg[1][2][kt], acc[1][2], 0, 0, 0);
      acc[1][3] = __builtin_amdgcn_mfma_f32_16x16x32_bf16(af, o_w[w][1][kt][lane], acc[1][3], 0, 0, 0);
    }

    // ---- redistribute: valid C rows {0,1} sit at q=0, e={0,1} (per block).
    // Target: lane (q,cl) gets (block q>>1, row q&1).
    float sh1[4], sh2[4], sh3[4], ag[4];
#pragma unroll
    for (int g = 0; g < 4; ++g) {
      sh1[g] = __shfl_xor(acc[0][g][1], 16, 64);  // q=1 <- q=0: b0 row1
      sh2[g] = __shfl_xor(acc[1][g][0], 32, 64);  // q=2 <- q=0: b1 row0
      sh3[g] = __shfl_xor(acc[1][g][1], 48, 64);  // q=3 <- q=0: b1 row1
    }
#pragma unroll
    for (int g = 0; g < 4; ++g)
      ag[g] = (q == 0) ? acc[0][g][0]
            : (q == 1) ? sh1[g]
            : (q == 2) ? sh2[g]
                       : sh3[g];

    // ---- EW: exactly one LSTM cell per lane.
    {
      float pi = ag[0] + bf2f(pv[0]);
      float pf = ag[1] + bf2f(pv[1]);
      float pg = ag[2] + bf2f(pv[2]);
      float po = ag[3] + bf2f(pv[3]);
      float ig = sig_f(pi), fg = sig_f(pf), gg = tanh_f(pg), og = sig_f(po);
      float cn = fg * creg + ig * gg;
      creg = cn;
      float hn = og * tanh_f(cn);
      if (!lastt) {
        int wb = rq * 512 + ((colq * 2) ^ (rq << 4));
        hw[wb >> 1] = f2bf(hn);
      } else {
        out[(size_t)(x * 2 + rq) * 256 + colq] = hn;
        out[65536 + (size_t)(x * 2 + rq) * 256 + colq] = cn;
      }
    }

    __syncthreads();  // h(t+1) complete before step t+1 reads it
  }
}

extern "C" void kernel_launch(void* const* d_in, const int* in_sizes, int n_in,
                              void* d_out, int out_size, void* d_ws, size_t ws_size,
                              hipStream_t stream) {
  const float* x = (const float*)d_in[0];
  const float* wx0 = (const float*)d_in[1];
  const float* wx1 = (const float*)d_in[5];
  const float* wx2 = (const float*)d_in[9];
  const float* wx3 = (const float*)d_in[13];
  const float* wh0 = (const float*)d_in[3];
  const float* wh1 = (const float*)d_in[7];
  const float* wh2 = (const float*)d_in[11];
  const float* wh3 = (const float*)d_in[15];
  const float* bx0 = (const float*)d_in[2];
  const float* bx1 = (const float*)d_in[6];
  const float* bx2 = (const float*)d_in[10];
  const float* bx3 = (const float*)d_in[14];
  const float* bh0 = (const float*)d_in[4];
  const float* bh1 = (const float*)d_in[8];
  const float* bh2 = (const float*)d_in[12];
  const float* bh3 = (const float*)d_in[16];

  char* ws = (char*)d_ws;
  unsigned short* WxT = (unsigned short*)(ws + 0);          // dead after precompute
  unsigned short* WhT = (unsigned short*)(ws + 524288);
  float* bcat = (float*)(ws + 1048576);
  unsigned short* P = (unsigned short*)(ws + 1052672);      // [t][rg16][n][16] bf16

  lstm_prep_w<<<dim3(8, 8, 8), 256, 0, stream>>>(wx0, wx1, wx2, wx3,
                                                 wh0, wh1, wh2, wh3, WxT, WhT);
  lstm_prep_b<<<4, 256, 0, stream>>>(bx0, bx1, bx2, bx3, bh0, bh1, bh2, bh3, bcat);
  lstm_precompute<<<dim3(255, 4), 256, 0, stream>>>(x, WxT, bcat, P);
  lstm_recurrent<<<dim3(128), 512, 0, stream>>>(WhT, P, (float*)d_out);
}

// Round 15
// 817.551 us; speedup vs baseline: 1.1396x; 1.1396x over previous
//
#include <hip/hip_runtime.h>

// LSTM_77893526880768: B=T=F=H=256.  256 independent row-chains, 255 steps.
//
// v24 = v22 recurrent VERBATIM (591us, reproduced 3x) + precompute with
//       in-block occupancy (512 thr, 2 waves/SIMD) at v22's traffic.
//
// Evidence ladder (recurrent): structurally pinned at ~1630cy/step
// (2 rows/WG minimum of the rows/WG sweep; 192-reg weight split unique
// no-spill point; conflicts/shuffles overlapped; clock fixed ~700-750MHz,
// 6x independent checks).  Untouched.
//
// Precompute evidence: v22 (255 WGs x 256thr, 1 wave/SIMD) ~110-130us;
// v23 row-split (1020 WGs) REGRESSED +144us -- every WG streams the full
// WxT afrag sequence (addresses row-independent), so 4x WGs = 4x weight
// request traffic (0.5GB -> 2GB L2).  Lesson: occupancy must come from
// INSIDE the block.  v24: grid (255,1) kept (x read once, WxT requests
// minimal), 512 threads = 8 waves = 2 waves/SIMD; wave w owns rows
// [32w, 32w+32) (rt 0..1).  bfrag 64 regs, total ~135 <= 256 cap.
// Same MFMA count, same P bytes.
//
// Workspace layout:
//   [0, 512K)       WxT bf16   (dead after precompute)
//   [512K, 1M)      WhT bf16
//   [1M, 1M+4K)     bcat fp32
//   [1M+4K, ...)    P bf16  [t][rg16][n][16] = 133,693,440 B

#define STEPS 255

typedef short bf16x8 __attribute__((ext_vector_type(8)));
typedef short bf16x4 __attribute__((ext_vector_type(4)));
typedef float f32x4  __attribute__((ext_vector_type(4)));

__device__ inline unsigned short f2bf(float f) {
  unsigned int u = __float_as_uint(f);
  unsigned int r = (u + 0x7FFFu + ((u >> 16) & 1u)) >> 16;  // RNE
  return (unsigned short)r;
}
__device__ inline float bf2f(unsigned short s) {
  return __uint_as_float(((unsigned int)s) << 16);
}
__device__ inline float sig_f(float x) {
  float e = exp2f(-1.442695041f * x);
  return __builtin_amdgcn_rcpf(1.0f + e);
}
__device__ inline float tanh_f(float x) {
  float e = exp2f(-2.885390082f * x);
  return 2.0f * __builtin_amdgcn_rcpf(1.0f + e) - 1.0f;
}

// ---------- prep: W transpose (W[k][j] fp32 -> WT[g*256+j][k] bf16) ----------
__global__ __launch_bounds__(256) void lstm_prep_w(
    const float* __restrict__ m0, const float* __restrict__ m1,
    const float* __restrict__ m2, const float* __restrict__ m3,
    const float* __restrict__ m4, const float* __restrict__ m5,
    const float* __restrict__ m6, const float* __restrict__ m7,
    unsigned short* __restrict__ WxT, unsigned short* __restrict__ WhT) {
  const float* mats[8] = {m0, m1, m2, m3, m4, m5, m6, m7};
  int mat = blockIdx.z;
  const float* W = mats[mat];
  unsigned short* out = (mat < 4 ? WxT : WhT) + (size_t)(mat & 3) * 256 * 256;
  int kblk = blockIdx.x * 32, jblk = blockIdx.y * 32;
  __shared__ float tile[32][33];
  int tx = threadIdx.x & 31, ty = threadIdx.x >> 5;
#pragma unroll
  for (int i = 0; i < 4; ++i) {
    int kk = ty + i * 8;
    tile[kk][tx] = W[(size_t)(kblk + kk) * 256 + jblk + tx];
  }
  __syncthreads();
#pragma unroll
  for (int i = 0; i < 4; ++i) {
    int jj = ty + i * 8;
    out[(size_t)(jblk + jj) * 256 + kblk + tx] = f2bf(tile[tx][jj]);
  }
}

// ---------- prep: bias fold ----------
__global__ void lstm_prep_b(
    const float* __restrict__ bx0, const float* __restrict__ bx1,
    const float* __restrict__ bx2, const float* __restrict__ bx3,
    const float* __restrict__ bh0, const float* __restrict__ bh1,
    const float* __restrict__ bh2, const float* __restrict__ bh3,
    float* __restrict__ bcat) {
  const float* bx[4] = {bx0, bx1, bx2, bx3};
  const float* bh[4] = {bh0, bh1, bh2, bh3};
  int i = blockIdx.x * 256 + threadIdx.x;
  int g = i >> 8, j = i & 255;
  bcat[i] = bx[g][j] + bh[g][j];
}

// ---------- precompute: P[t][rg16][n][rl] = bcat[n] + sum_k x[r,t,k] Wx[k,n] ----------
// v24: grid (255,1), 512 threads (8 waves, 2/SIMD).  Wave w owns rows
// [32w, 32w+32) (rt 0..1; rg16 = 2w+rt).  x read once chip-wide; WxT
// afrag stream per wave (L2-served).
__global__ __launch_bounds__(512, 2) void lstm_precompute(
    const float* __restrict__ x, const unsigned short* __restrict__ WxT,
    const float* __restrict__ bcat, unsigned short* __restrict__ P) {
  int t = blockIdx.x;
  int tid = threadIdx.x;
  int w = tid >> 6, lane = tid & 63, q = lane >> 4, cl = lane & 15;
  int rbase = w * 32;

  bf16x8 bfrag[8][2];
#pragma unroll
  for (int kt = 0; kt < 8; ++kt) {
    int k0 = kt * 32 + q * 8;
#pragma unroll
    for (int rt = 0; rt < 2; ++rt) {
      const float* xp = x + (((size_t)(rbase + rt * 16 + cl) * 256 + t) * 256 + k0);
      f32x4 lo = *(const f32x4*)xp;
      f32x4 hi = *(const f32x4*)(xp + 4);
      bf16x8 bv;
      bv[0] = (short)f2bf(lo[0]); bv[1] = (short)f2bf(lo[1]);
      bv[2] = (short)f2bf(lo[2]); bv[3] = (short)f2bf(lo[3]);
      bv[4] = (short)f2bf(hi[0]); bv[5] = (short)f2bf(hi[1]);
      bv[6] = (short)f2bf(hi[2]); bv[7] = (short)f2bf(hi[3]);
      bfrag[kt][rt] = bv;
    }
  }

  for (int nbi = 0; nbi < 16; ++nbi) {
    int nblk = nbi * 64;
    f32x4 acc[4][2];
#pragma unroll
    for (int a = 0; a < 4; ++a)
#pragma unroll
      for (int b = 0; b < 2; ++b) acc[a][b] = f32x4{0.f, 0.f, 0.f, 0.f};

#pragma unroll
    for (int kt = 0; kt < 8; ++kt) {
      int k0 = kt * 32 + q * 8;
      bf16x8 afrag[4];
#pragma unroll
      for (int mt = 0; mt < 4; ++mt)
        afrag[mt] = *(const bf16x8*)(WxT + (size_t)(nblk + mt * 16 + cl) * 256 + k0);
#pragma unroll
      for (int mt = 0; mt < 4; ++mt)
#pragma unroll
        for (int rt = 0; rt < 2; ++rt)
          acc[mt][rt] = __builtin_amdgcn_mfma_f32_16x16x32_bf16(
              afrag[mt], bfrag[kt][rt], acc[mt][rt], 0, 0, 0);
    }
#pragma unroll
    for (int mt = 0; mt < 4; ++mt) {
#pragma unroll
      for (int reg = 0; reg < 4; ++reg) {
        int n = nblk + mt * 16 + q * 4 + reg;
        float bb = bcat[n];
#pragma unroll
        for (int rt = 0; rt < 2; ++rt) {
          int rg16 = w * 2 + rt;  // = global row >> 4
          P[(((size_t)t * 16 + rg16) * 1024 + n) * 16 + cl] = f2bf(acc[mt][rt][reg] + bb);
        }
      }
    }
  }
}

// ---------- recurrent (v17/v22, verified 591us): 128 WGs x 2 rows ----------
__global__ __launch_bounds__(512, 2) void lstm_recurrent(
    const unsigned short* __restrict__ WhT,
    const unsigned short* __restrict__ P,
    float* __restrict__ out) {
  // o-gate B-frags: [wave][block][kt][lane] bf16x8 = 128 KB (v5-proven layout)
  __shared__ bf16x8 o_w[8][2][8][64];
  // h double buffer, XOR-swizzled: byte ^= ((row&7)<<4).  16 KB.
  // Rows 0..1 live; rows 2..15 stay zero forever (A-tile zero-padding).
  __shared__ unsigned short hbuf[2][16 * 256];

  int tid = threadIdx.x;
  int w = tid >> 6, lane = tid & 63, q = lane >> 4, cl = lane & 15;
  // XCD swizzle (v17-proven): the 8 WGs sharing P lines (same x>>3) get
  // identical b%8 -> one XCD -> each P line fetched into exactly one L2.
  int b_ = blockIdx.x;
  int x = (b_ & 7) * 16 + (b_ >> 3);  // bijective 0..127
  int rg16 = x >> 3;            // P row-group (global row >> 4)
  int idxb = (x & 7) * 2;       // P idx15 base for this WG's rows

  // ---- stage o-gate tiles into LDS: 8192 16B-chunks, 16 per thread
  for (int i = 0; i < 16; ++i) {
    int idx = tid + i * 512;
    int sw = idx >> 10, sb = (idx >> 9) & 1, skt = (idx >> 6) & 7, sl = idx & 63;
    int sq = sl >> 4, scl = sl & 15;
    int col = (2 * sw + sb) * 16 + scl;
    int k0 = skt * 32 + sq * 8;
    o_w[sw][sb][skt][sl] = *(const bf16x8*)(WhT + (size_t)(3 * 256 + col) * 256 + k0);
  }

  // ---- i,f,g gate tiles into VGPRs (static indexing only -- rule #20)
  bf16x8 wreg[2][3][8];  // [block][gate][kt] = 48 frags
#pragma unroll
  for (int b = 0; b < 2; ++b)
#pragma unroll
    for (int g = 0; g < 3; ++g)
#pragma unroll
      for (int kt = 0; kt < 8; ++kt) {
        int col = (2 * w + b) * 16 + cl;
        wreg[b][g][kt] =
            *(const bf16x8*)(WhT + (size_t)(g * 256 + col) * 256 + kt * 32 + q * 8);
      }

  // ---- zero BOTH h buffers (rows 2..15 never written; h_0 = 0)
  for (int i = tid; i < 4096; i += 512) ((unsigned int*)&hbuf[0][0])[i] = 0;

  // Memory clobber (v15-proven): rematerializing the wreg global loads
  // across this fence is illegal => weight values stay register-resident.
  asm volatile("" ::: "memory");
  __syncthreads();

  // A-read base (t-independent): row = cl, k-offset q*16 within kt-block,
  // swizzled.  Per kt: byte = abase ^ (kt*64) (bit-disjoint, v12-proven).
  int abase = cl * 512 + ((q * 16) ^ ((cl & 7) << 4));

  // EW ownership: lane (q,cl) owns the single cell
  //   block bq = q>>1, local row rq = q&1, col = 32w + bq*16 + cl.
  int bq = q >> 1, rq = q & 1;
  int colq = 32 * w + bq * 16 + cl;
  int idx15 = idxb + rq;

  float creg = 0.f;

  for (int t = 0; t < STEPS; ++t) {
    int rb = t & 1;
    bool lastt = (t == STEPS - 1);
    const unsigned short* hr = &hbuf[rb][0];
    unsigned short* hw = &hbuf[rb ^ 1][0];

    // P loads for this lane's cell: issued at step start, consumed after
    // the MFMA phase -> L2/HBM latency stays hidden.
    unsigned short pv[4];
    {
      const unsigned short* pp =
          P + (((size_t)t * 16 + rg16) * 1024 + colq) * 16 + idx15;
#pragma unroll
      for (int g = 0; g < 4; ++g) pv[g] = pp[(size_t)g * 4096];
    }

    // ---- MFMA: af loaded once per kt, feeds both blocks x 4 gates
    f32x4 acc[2][4];
#pragma unroll
    for (int b = 0; b < 2; ++b)
#pragma unroll
      for (int g = 0; g < 4; ++g) acc[b][g] = f32x4{0.f, 0.f, 0.f, 0.f};

#pragma unroll
    for (int kt = 0; kt < 8; ++kt) {
      bf16x8 af = *(const bf16x8*)(hr + ((abase ^ (kt * 64)) >> 1));
      acc[0][0] = __builtin_amdgcn_mfma_f32_16x16x32_bf16(af, wreg[0][0][kt], acc[0][0], 0, 0, 0);
      acc[0][1] = __builtin_amdgcn_mfma_f32_16x16x32_bf16(af, wreg[0][1][kt], acc[0][1], 0, 0, 0);
      acc[0][2] = __builtin_amdgcn_mfma_f32_16x16x32_bf16(af, wreg[0][2][kt], acc[0][2], 0, 0, 0);
      acc[0][3] = __builtin_amdgcn_mfma_f32_16x16x32_bf16(af, o_w[w][0][kt][lane], acc[0][3], 0, 0, 0);
      acc[1][0] = __builtin_amdgcn_mfma_f32_16x16x32_bf16(af, wreg[1][0][kt], acc[1][0], 0, 0, 0);
      acc[1][1] = __builtin_amdgcn_mfma_f32_16x16x32_bf16(af, wreg[1][1][kt], acc[1][1], 0, 0, 0);
      acc[1][2] = __builtin_amdgcn_mfma_f32_16x16x32_bf16(af, wreg[1][2][kt], acc[1][2], 0, 0, 0);
      acc[1][3] = __builtin_amdgcn_mfma_f32_16x16x32_bf16(af, o_w[w][1][kt][lane], acc[1][3], 0, 0, 0);
    }

    // ---- redistribute: valid C rows {0,1} sit at q=0, e={0,1} (per block).
    // Target: lane (q,cl) gets (block q>>1, row q&1).
    float sh1[4], sh2[4], sh3[4], ag[4];
#pragma unroll
    for (int g = 0; g < 4; ++g) {
      sh1[g] = __shfl_xor(acc[0][g][1], 16, 64);  // q=1 <- q=0: b0 row1
      sh2[g] = __shfl_xor(acc[1][g][0], 32, 64);  // q=2 <- q=0: b1 row0
      sh3[g] = __shfl_xor(acc[1][g][1], 48, 64);  // q=3 <- q=0: b1 row1
    }
#pragma unroll
    for (int g = 0; g < 4; ++g)
      ag[g] = (q == 0) ? acc[0][g][0]
            : (q == 1) ? sh1[g]
            : (q == 2) ? sh2[g]
                       : sh3[g];

    // ---- EW: exactly one LSTM cell per lane.
    {
      float pi = ag[0] + bf2f(pv[0]);
      float pf = ag[1] + bf2f(pv[1]);
      float pg = ag[2] + bf2f(pv[2]);
      float po = ag[3] + bf2f(pv[3]);
      float ig = sig_f(pi), fg = sig_f(pf), gg = tanh_f(pg), og = sig_f(po);
      float cn = fg * creg + ig * gg;
      creg = cn;
      float hn = og * tanh_f(cn);
      if (!lastt) {
        int wb = rq * 512 + ((colq * 2) ^ (rq << 4));
        hw[wb >> 1] = f2bf(hn);
      } else {
        out[(size_t)(x * 2 + rq) * 256 + colq] = hn;
        out[65536 + (size_t)(x * 2 + rq) * 256 + colq] = cn;
      }
    }

    __syncthreads();  // h(t+1) complete before step t+1 reads it
  }
}

extern "C" void kernel_launch(void* const* d_in, const int* in_sizes, int n_in,
                              void* d_out, int out_size, void* d_ws, size_t ws_size,
                              hipStream_t stream) {
  const float* x = (const float*)d_in[0];
  const float* wx0 = (const float*)d_in[1];
  const float* wx1 = (const float*)d_in[5];
  const float* wx2 = (const float*)d_in[9];
  const float* wx3 = (const float*)d_in[13];
  const float* wh0 = (const float*)d_in[3];
  const float* wh1 = (const float*)d_in[7];
  const float* wh2 = (const float*)d_in[11];
  const float* wh3 = (const float*)d_in[15];
  const float* bx0 = (const float*)d_in[2];
  const float* bx1 = (const float*)d_in[6];
  const float* bx2 = (const float*)d_in[10];
  const float* bx3 = (const float*)d_in[14];
  const float* bh0 = (const float*)d_in[4];
  const float* bh1 = (const float*)d_in[8];
  const float* bh2 = (const float*)d_in[12];
  const float* bh3 = (const float*)d_in[16];

  char* ws = (char*)d_ws;
  unsigned short* WxT = (unsigned short*)(ws + 0);          // dead after precompute
  unsigned short* WhT = (unsigned short*)(ws + 524288);
  float* bcat = (float*)(ws + 1048576);
  unsigned short* P = (unsigned short*)(ws + 1052672);      // [t][rg16][n][16] bf16

  lstm_prep_w<<<dim3(8, 8, 8), 256, 0, stream>>>(wx0, wx1, wx2, wx3,
                                                 wh0, wh1, wh2, wh3, WxT, WhT);
  lstm_prep_b<<<4, 256, 0, stream>>>(bx0, bx1, bx2, bx3, bh0, bh1, bh2, bh3, bcat);
  lstm_precompute<<<dim3(255, 1), 512, 0, stream>>>(x, WxT, bcat, P);
  lstm_recurrent<<<dim3(128), 512, 0, stream>>>(WhT, P, (float*)d_out);
}

// Round 16
// 787.845 us; speedup vs baseline: 1.1826x; 1.0377x over previous
//
#include <hip/hip_runtime.h>

// LSTM_77893526880768: B=T=F=H=256.  256 independent row-chains, 255 steps.
//
// v25 == v22 EXACTLY (best verified total: 782.5us).  Final configuration.
//
// Why this is the endpoint (evidence ladder, 15 rounds):
//   RECURRENT (591us, reproduced 4x): structurally pinned ~1630cy/step at
//   the fixed ~700-750MHz clock (6 independent MFMA-cycle checks; clock
//   does not respond to load -- v13 heaters).  Budget: per-CU MFMA issue
//   640cy (512 MFMAs/CU/step, invariant across every WG shape tried) +
//   o_w LDS 128KB/step (weights-in-regs falsified by v18/v19 spills; 192
//   frag-regs + o-gate-LDS is the unique no-spill split) + EW tail +
//   barrier.  rows/WG sweep {16,8,2,1} -> {3670,3100,*1630*,1755} cy.
//   Cross-WG M-packing dead: any cross-WG h exchange costs ~4.7us/round
//   (3 protocol flavors + pre-posted flags all equal).  Conflicts/
//   shuffles/predication are overlapped, not critical (v20/v21 nulls).
//   PRECOMPUTE (~110us): config sweep {256thr(v22), 4-WG-split(v23),
//   512thr(v24)} -> v22 minimum (+144/+37 for the others: WxT request
//   traffic scales with wave count; occupancy adds contention, not hiding).
//   x read exactly once (v22 dedup, -40us vs duplicated).
//
// Workspace layout:
//   [0, 512K)       WxT bf16   (dead after precompute)
//   [512K, 1M)      WhT bf16
//   [1M, 1M+4K)     bcat fp32
//   [1M+4K, ...)    P bf16  [t][rg16][n][16] = 133,693,440 B

#define STEPS 255

typedef short bf16x8 __attribute__((ext_vector_type(8)));
typedef short bf16x4 __attribute__((ext_vector_type(4)));
typedef float f32x4  __attribute__((ext_vector_type(4)));

__device__ inline unsigned short f2bf(float f) {
  unsigned int u = __float_as_uint(f);
  unsigned int r = (u + 0x7FFFu + ((u >> 16) & 1u)) >> 16;  // RNE
  return (unsigned short)r;
}
__device__ inline float bf2f(unsigned short s) {
  return __uint_as_float(((unsigned int)s) << 16);
}
__device__ inline float sig_f(float x) {
  float e = exp2f(-1.442695041f * x);
  return __builtin_amdgcn_rcpf(1.0f + e);
}
__device__ inline float tanh_f(float x) {
  float e = exp2f(-2.885390082f * x);
  return 2.0f * __builtin_amdgcn_rcpf(1.0f + e) - 1.0f;
}

// ---------- prep: W transpose (W[k][j] fp32 -> WT[g*256+j][k] bf16) ----------
__global__ __launch_bounds__(256) void lstm_prep_w(
    const float* __restrict__ m0, const float* __restrict__ m1,
    const float* __restrict__ m2, const float* __restrict__ m3,
    const float* __restrict__ m4, const float* __restrict__ m5,
    const float* __restrict__ m6, const float* __restrict__ m7,
    unsigned short* __restrict__ WxT, unsigned short* __restrict__ WhT) {
  const float* mats[8] = {m0, m1, m2, m3, m4, m5, m6, m7};
  int mat = blockIdx.z;
  const float* W = mats[mat];
  unsigned short* out = (mat < 4 ? WxT : WhT) + (size_t)(mat & 3) * 256 * 256;
  int kblk = blockIdx.x * 32, jblk = blockIdx.y * 32;
  __shared__ float tile[32][33];
  int tx = threadIdx.x & 31, ty = threadIdx.x >> 5;
#pragma unroll
  for (int i = 0; i < 4; ++i) {
    int kk = ty + i * 8;
    tile[kk][tx] = W[(size_t)(kblk + kk) * 256 + jblk + tx];
  }
  __syncthreads();
#pragma unroll
  for (int i = 0; i < 4; ++i) {
    int jj = ty + i * 8;
    out[(size_t)(jblk + jj) * 256 + kblk + tx] = f2bf(tile[tx][jj]);
  }
}

// ---------- prep: bias fold ----------
__global__ void lstm_prep_b(
    const float* __restrict__ bx0, const float* __restrict__ bx1,
    const float* __restrict__ bx2, const float* __restrict__ bx3,
    const float* __restrict__ bh0, const float* __restrict__ bh1,
    const float* __restrict__ bh2, const float* __restrict__ bh3,
    float* __restrict__ bcat) {
  const float* bx[4] = {bx0, bx1, bx2, bx3};
  const float* bh[4] = {bh0, bh1, bh2, bh3};
  int i = blockIdx.x * 256 + threadIdx.x;
  int g = i >> 8, j = i & 255;
  bcat[i] = bx[g][j] + bh[g][j];
}

// ---------- precompute: P[t][rg16][n][rl] = bcat[n] + sum_k x[r,t,k] Wx[k,n] ----------
// v22-proven optimum: grid (255,1), 256 thr; x-fragments built ONCE,
// all 16 n-blocks in one WG.
__global__ __launch_bounds__(256, 1) void lstm_precompute(
    const float* __restrict__ x, const unsigned short* __restrict__ WxT,
    const float* __restrict__ bcat, unsigned short* __restrict__ P) {
  int t = blockIdx.x;
  int tid = threadIdx.x;
  int w = tid >> 6, lane = tid & 63, q = lane >> 4, cl = lane & 15;
  int rbase = w * 64;

  bf16x8 bfrag[8][4];
#pragma unroll
  for (int kt = 0; kt < 8; ++kt) {
    int k0 = kt * 32 + q * 8;
#pragma unroll
    for (int rt = 0; rt < 4; ++rt) {
      const float* xp = x + (((size_t)(rbase + rt * 16 + cl) * 256 + t) * 256 + k0);
      f32x4 lo = *(const f32x4*)xp;
      f32x4 hi = *(const f32x4*)(xp + 4);
      bf16x8 bv;
      bv[0] = (short)f2bf(lo[0]); bv[1] = (short)f2bf(lo[1]);
      bv[2] = (short)f2bf(lo[2]); bv[3] = (short)f2bf(lo[3]);
      bv[4] = (short)f2bf(hi[0]); bv[5] = (short)f2bf(hi[1]);
      bv[6] = (short)f2bf(hi[2]); bv[7] = (short)f2bf(hi[3]);
      bfrag[kt][rt] = bv;
    }
  }

  for (int nbi = 0; nbi < 16; ++nbi) {
    int nblk = nbi * 64;
    f32x4 acc[4][4];
#pragma unroll
    for (int a = 0; a < 4; ++a)
#pragma unroll
      for (int b = 0; b < 4; ++b) acc[a][b] = f32x4{0.f, 0.f, 0.f, 0.f};

#pragma unroll
    for (int kt = 0; kt < 8; ++kt) {
      int k0 = kt * 32 + q * 8;
      bf16x8 afrag[4];
#pragma unroll
      for (int mt = 0; mt < 4; ++mt)
        afrag[mt] = *(const bf16x8*)(WxT + (size_t)(nblk + mt * 16 + cl) * 256 + k0);
#pragma unroll
      for (int mt = 0; mt < 4; ++mt)
#pragma unroll
        for (int rt = 0; rt < 4; ++rt)
          acc[mt][rt] = __builtin_amdgcn_mfma_f32_16x16x32_bf16(
              afrag[mt], bfrag[kt][rt], acc[mt][rt], 0, 0, 0);
    }
#pragma unroll
    for (int mt = 0; mt < 4; ++mt) {
#pragma unroll
      for (int reg = 0; reg < 4; ++reg) {
        int n = nblk + mt * 16 + q * 4 + reg;
        float bb = bcat[n];
#pragma unroll
        for (int rt = 0; rt < 4; ++rt) {
          int rg16 = w * 4 + rt;  // = r>>4
          P[(((size_t)t * 16 + rg16) * 1024 + n) * 16 + cl] = f2bf(acc[mt][rt][reg] + bb);
        }
      }
    }
  }
}

// ---------- recurrent (v17/v22, verified 591us x4): 128 WGs x 2 rows ----------
__global__ __launch_bounds__(512, 2) void lstm_recurrent(
    const unsigned short* __restrict__ WhT,
    const unsigned short* __restrict__ P,
    float* __restrict__ out) {
  // o-gate B-frags: [wave][block][kt][lane] bf16x8 = 128 KB (v5-proven layout)
  __shared__ bf16x8 o_w[8][2][8][64];
  // h double buffer, XOR-swizzled: byte ^= ((row&7)<<4).  16 KB.
  // Rows 0..1 live; rows 2..15 stay zero forever (A-tile zero-padding).
  __shared__ unsigned short hbuf[2][16 * 256];

  int tid = threadIdx.x;
  int w = tid >> 6, lane = tid & 63, q = lane >> 4, cl = lane & 15;
  // XCD swizzle (v17-proven): the 8 WGs sharing P lines (same x>>3) get
  // identical b%8 -> one XCD -> each P line fetched into exactly one L2.
  int b_ = blockIdx.x;
  int x = (b_ & 7) * 16 + (b_ >> 3);  // bijective 0..127
  int rg16 = x >> 3;            // P row-group (global row >> 4)
  int idxb = (x & 7) * 2;       // P idx15 base for this WG's rows

  // ---- stage o-gate tiles into LDS: 8192 16B-chunks, 16 per thread
  for (int i = 0; i < 16; ++i) {
    int idx = tid + i * 512;
    int sw = idx >> 10, sb = (idx >> 9) & 1, skt = (idx >> 6) & 7, sl = idx & 63;
    int sq = sl >> 4, scl = sl & 15;
    int col = (2 * sw + sb) * 16 + scl;
    int k0 = skt * 32 + sq * 8;
    o_w[sw][sb][skt][sl] = *(const bf16x8*)(WhT + (size_t)(3 * 256 + col) * 256 + k0);
  }

  // ---- i,f,g gate tiles into VGPRs (static indexing only -- rule #20)
  bf16x8 wreg[2][3][8];  // [block][gate][kt] = 48 frags
#pragma unroll
  for (int b = 0; b < 2; ++b)
#pragma unroll
    for (int g = 0; g < 3; ++g)
#pragma unroll
      for (int kt = 0; kt < 8; ++kt) {
        int col = (2 * w + b) * 16 + cl;
        wreg[b][g][kt] =
            *(const bf16x8*)(WhT + (size_t)(g * 256 + col) * 256 + kt * 32 + q * 8);
      }

  // ---- zero BOTH h buffers (rows 2..15 never written; h_0 = 0)
  for (int i = tid; i < 4096; i += 512) ((unsigned int*)&hbuf[0][0])[i] = 0;

  // Memory clobber (v15-proven): rematerializing the wreg global loads
  // across this fence is illegal => weight values stay register-resident.
  asm volatile("" ::: "memory");
  __syncthreads();

  // A-read base (t-independent): row = cl, k-offset q*16 within kt-block,
  // swizzled.  Per kt: byte = abase ^ (kt*64) (bit-disjoint, v12-proven).
  int abase = cl * 512 + ((q * 16) ^ ((cl & 7) << 4));

  // EW ownership: lane (q,cl) owns the single cell
  //   block bq = q>>1, local row rq = q&1, col = 32w + bq*16 + cl.
  int bq = q >> 1, rq = q & 1;
  int colq = 32 * w + bq * 16 + cl;
  int idx15 = idxb + rq;

  float creg = 0.f;

  for (int t = 0; t < STEPS; ++t) {
    int rb = t & 1;
    bool lastt = (t == STEPS - 1);
    const unsigned short* hr = &hbuf[rb][0];
    unsigned short* hw = &hbuf[rb ^ 1][0];

    // P loads for this lane's cell: issued at step start, consumed after
    // the MFMA phase -> L2/HBM latency stays hidden.
    unsigned short pv[4];
    {
      const unsigned short* pp =
          P + (((size_t)t * 16 + rg16) * 1024 + colq) * 16 + idx15;
#pragma unroll
      for (int g = 0; g < 4; ++g) pv[g] = pp[(size_t)g * 4096];
    }

    // ---- MFMA: af loaded once per kt, feeds both blocks x 4 gates
    f32x4 acc[2][4];
#pragma unroll
    for (int b = 0; b < 2; ++b)
#pragma unroll
      for (int g = 0; g < 4; ++g) acc[b][g] = f32x4{0.f, 0.f, 0.f, 0.f};

#pragma unroll
    for (int kt = 0; kt < 8; ++kt) {
      bf16x8 af = *(const bf16x8*)(hr + ((abase ^ (kt * 64)) >> 1));
      acc[0][0] = __builtin_amdgcn_mfma_f32_16x16x32_bf16(af, wreg[0][0][kt], acc[0][0], 0, 0, 0);
      acc[0][1] = __builtin_amdgcn_mfma_f32_16x16x32_bf16(af, wreg[0][1][kt], acc[0][1], 0, 0, 0);
      acc[0][2] = __builtin_amdgcn_mfma_f32_16x16x32_bf16(af, wreg[0][2][kt], acc[0][2], 0, 0, 0);
      acc[0][3] = __builtin_amdgcn_mfma_f32_16x16x32_bf16(af, o_w[w][0][kt][lane], acc[0][3], 0, 0, 0);
      acc[1][0] = __builtin_amdgcn_mfma_f32_16x16x32_bf16(af, wreg[1][0][kt], acc[1][0], 0, 0, 0);
      acc[1][1] = __builtin_amdgcn_mfma_f32_16x16x32_bf16(af, wreg[1][1][kt], acc[1][1], 0, 0, 0);
      acc[1][2] = __builtin_amdgcn_mfma_f32_16x16x32_bf16(af, wreg[1][2][kt], acc[1][2], 0, 0, 0);
      acc[1][3] = __builtin_amdgcn_mfma_f32_16x16x32_bf16(af, o_w[w][1][kt][lane], acc[1][3], 0, 0, 0);
    }

    // ---- redistribute: valid C rows {0,1} sit at q=0, e={0,1} (per block).
    // Target: lane (q,cl) gets (block q>>1, row q&1).
    float sh1[4], sh2[4], sh3[4], ag[4];
#pragma unroll
    for (int g = 0; g < 4; ++g) {
      sh1[g] = __shfl_xor(acc[0][g][1], 16, 64);  // q=1 <- q=0: b0 row1
      sh2[g] = __shfl_xor(acc[1][g][0], 32, 64);  // q=2 <- q=0: b1 row0
      sh3[g] = __shfl_xor(acc[1][g][1], 48, 64);  // q=3 <- q=0: b1 row1
    }
#pragma unroll
    for (int g = 0; g < 4; ++g)
      ag[g] = (q == 0) ? acc[0][g][0]
            : (q == 1) ? sh1[g]
            : (q == 2) ? sh2[g]
                       : sh3[g];

    // ---- EW: exactly one LSTM cell per lane.
    {
      float pi = ag[0] + bf2f(pv[0]);
      float pf = ag[1] + bf2f(pv[1]);
      float pg = ag[2] + bf2f(pv[2]);
      float po = ag[3] + bf2f(pv[3]);
      float ig = sig_f(pi), fg = sig_f(pf), gg = tanh_f(pg), og = sig_f(po);
      float cn = fg * creg + ig * gg;
      creg = cn;
      float hn = og * tanh_f(cn);
      if (!lastt) {
        int wb = rq * 512 + ((colq * 2) ^ (rq << 4));
        hw[wb >> 1] = f2bf(hn);
      } else {
        out[(size_t)(x * 2 + rq) * 256 + colq] = hn;
        out[65536 + (size_t)(x * 2 + rq) * 256 + colq] = cn;
      }
    }

    __syncthreads();  // h(t+1) complete before step t+1 reads it
  }
}

extern "C" void kernel_launch(void* const* d_in, const int* in_sizes, int n_in,
                              void* d_out, int out_size, void* d_ws, size_t ws_size,
                              hipStream_t stream) {
  const float* x = (const float*)d_in[0];
  const float* wx0 = (const float*)d_in[1];
  const float* wx1 = (const float*)d_in[5];
  const float* wx2 = (const float*)d_in[9];
  const float* wx3 = (const float*)d_in[13];
  const float* wh0 = (const float*)d_in[3];
  const float* wh1 = (const float*)d_in[7];
  const float* wh2 = (const float*)d_in[11];
  const float* wh3 = (const float*)d_in[15];
  const float* bx0 = (const float*)d_in[2];
  const float* bx1 = (const float*)d_in[6];
  const float* bx2 = (const float*)d_in[10];
  const float* bx3 = (const float*)d_in[14];
  const float* bh0 = (const float*)d_in[4];
  const float* bh1 = (const float*)d_in[8];
  const float* bh2 = (const float*)d_in[12];
  const float* bh3 = (const float*)d_in[16];

  char* ws = (char*)d_ws;
  unsigned short* WxT = (unsigned short*)(ws + 0);          // dead after precompute
  unsigned short* WhT = (unsigned short*)(ws + 524288);
  float* bcat = (float*)(ws + 1048576);
  unsigned short* P = (unsigned short*)(ws + 1052672);      // [t][rg16][n][16] bf16

  lstm_prep_w<<<dim3(8, 8, 8), 256, 0, stream>>>(wx0, wx1, wx2, wx3,
                                                 wh0, wh1, wh2, wh3, WxT, WhT);
  lstm_prep_b<<<4, 256, 0, stream>>>(bx0, bx1, bx2, bx3, bh0, bh1, bh2, bh3, bcat);
  lstm_precompute<<<dim3(255, 1), 256, 0, stream>>>(x, WxT, bcat, P);
  lstm_recurrent<<<dim3(128), 512, 0, stream>>>(WhT, P, (float*)d_out);
}